// Round 19
// baseline (37.250 us; speedup 1.0000x reference)
//
#include <hip/hip_runtime.h>

namespace {

typedef short  bf16x8 __attribute__((ext_vector_type(8)));
typedef float  f32x4  __attribute__((ext_vector_type(4)));

constexpr int D = 1024;   // in_features
constexpr int O = 1024;   // out_features

// fp32 -> bf16 bits, round-to-nearest-even
__device__ __forceinline__ short f2bf(float f) {
    unsigned u = __builtin_bit_cast(unsigned, f);
    u += 0x7fffu + ((u >> 16) & 1u);
    return (short)(u >> 16);
}

__device__ __forceinline__ bf16x8 cvt8(const float4 a, const float4 b) {
    bf16x8 v;
    v[0] = f2bf(a.x); v[1] = f2bf(a.y); v[2] = f2bf(a.z); v[3] = f2bf(a.w);
    v[4] = f2bf(b.x); v[5] = f2bf(b.y); v[6] = f2bf(b.z); v[7] = f2bf(b.w);
    return v;
}

__device__ __forceinline__ float4 ld4(const float* p) {
    return *reinterpret_cast<const float4*>(p);
}

struct StageRegs { float4 a[4]; float4 b[4]; };

__device__ __forceinline__ void issue_dw(const float* __restrict__ dw, int c, int t,
                                         StageRegs& r) {
#pragma unroll
    for (int i = 0; i < 4; ++i) {
        const int e = i * 512 + t, kr = e >> 5, cc = e & 31;
        const float* sp = dw + (size_t)kr * D + c * 256 + cc * 8;
        r.a[i] = ld4(sp);
        r.b[i] = ld4(sp + 4);
    }
}
__device__ __forceinline__ void write_p1(short* buf, int t, const StageRegs& r) {
#pragma unroll
    for (int i = 0; i < 4; ++i) {
        const int e = i * 512 + t, kr = e >> 5, cc = e & 31;
        *reinterpret_cast<bf16x8*>(&buf[kr * 264 + cc * 8]) = cvt8(r.a[i], r.b[i]);
    }
}

// ---------------- Kernel A: low = bf16(alpha*4 * hs @ dw^T) ----------------
// UNCHANGED (measured ~6.7 us — L3-fed read stream near its ceiling).
__global__ void __launch_bounds__(512) lora_low_k(
        const float* __restrict__ hs,     // [16384][1024] f32
        const float* __restrict__ alpha,  // [4][4]
        const float* __restrict__ dw,     // [64][1024] f32  (k*16+r major)
        short* __restrict__ lowg) {       // [16384][64] bf16 out
    __shared__ __align__(16) short bs[2][64 * 264];  // 67.6 KB dw chunks
    __shared__ float pacc[4][16][64];                // 16 KB split-K partials

    const int t    = threadIdx.x;
    const int w    = t >> 6;
    const int lane = t & 63;
    const int fr   = lane & 15;
    const int kgi  = lane >> 4;
    const int kg   = kgi * 8;
    const int rt   = w >> 1;            // row-tile 0..3
    const int kh   = w & 1;             // K-half
    const int rowblk = blockIdx.x * 64;
    const int b      = rowblk >> 12;    // batch (blocks never straddle)
    const int myrow  = rowblk + rt * 16 + fr;
    const float* apb = hs + (size_t)myrow * D + kh * 128 + kg;

    StageRegs rg;
    issue_dw(dw, 0, t, rg);

    float4 pf[8];                                  // hs chunk-0 prefetch
#pragma unroll
    for (int ks = 0; ks < 4; ++ks) {
        pf[2 * ks]     = ld4(apb + ks * 32);
        pf[2 * ks + 1] = ld4(apb + ks * 32 + 4);
    }

    write_p1(&bs[0][0], t, rg);
    __syncthreads();

    f32x4 acc[4];
#pragma unroll
    for (int nt = 0; nt < 4; ++nt) acc[nt] = (f32x4){0.f, 0.f, 0.f, 0.f};

#pragma unroll
    for (int c = 0; c < 4; ++c) {
        bf16x8 av[4];
#pragma unroll
        for (int ks = 0; ks < 4; ++ks) av[ks] = cvt8(pf[2 * ks], pf[2 * ks + 1]);

        if (c < 3) {
            const float* ap = apb + (c + 1) * 256;
#pragma unroll
            for (int ks = 0; ks < 4; ++ks) {
                pf[2 * ks]     = ld4(ap + ks * 32);
                pf[2 * ks + 1] = ld4(ap + ks * 32 + 4);
            }
            issue_dw(dw, c + 1, t, rg);
        }

#pragma unroll
        for (int ks = 0; ks < 4; ++ks)
#pragma unroll
            for (int nt = 0; nt < 4; ++nt) {
                const bf16x8 bv = *reinterpret_cast<const bf16x8*>(
                    &bs[c & 1][(nt * 16 + fr) * 264 + kh * 128 + ks * 32 + kg]);
                acc[nt] = __builtin_amdgcn_mfma_f32_16x16x32_bf16(av[ks], bv, acc[nt], 0, 0, 0);
            }

        if (c < 3) {
            write_p1(&bs[(c + 1) & 1][0], t, rg);
            __syncthreads();
        }
    }

    // split-K combine; scale by alpha*4; write bf16 low to global
    if (kh) {
#pragma unroll
        for (int nt = 0; nt < 4; ++nt)
#pragma unroll
            for (int j = 0; j < 4; ++j)
                pacc[rt][nt * 4 + j][lane] = acc[nt][j];
    }
    __syncthreads();
    if (!kh) {
#pragma unroll
        for (int nt = 0; nt < 4; ++nt) {
            const float sc = alpha[b * 4 + nt] * 4.0f;   // NETWORK_ALPHA/RANK = 4
#pragma unroll
            for (int j = 0; j < 4; ++j) {
                const float v = (acc[nt][j] + pacc[rt][nt * 4 + j][lane]) * sc;
                lowg[(size_t)(rowblk + rt * 16 + kgi * 4 + j) * 64 + nt * 16 + fr] = f2bf(v);
            }
        }
    }
}

// ---------------- Kernel B: out = low @ wt2^T (contiguous NT store bursts) ----------------
// R17 structure; output stores are NONTEMPORAL via clang ext-vector f32x4
// (bypass L2 allocation — out is write-once, never read; 64 MB streaming
// through the 4 MB/XCD L2 is the suspected dirty-eviction bottleneck).
__global__ void __launch_bounds__(512) lora_up_k(
        const short* __restrict__ lowg,   // [16384][64] bf16
        const float* __restrict__ uw,     // [4][1024][16] f32
        float* __restrict__ out) {        // [16384][1024] f32
    __shared__ __align__(16) float lbuf[2][16][1026];   // 2 x 65.7 KB

    const int t    = threadIdx.x;
    const int w    = t >> 6;            // o-eighth (cols w*128..+128)
    const int lane = t & 63;
    const int fr   = lane & 15;
    const int kgi  = lane >> 4;
    const int kg   = kgi * 8;
    const int row0 = blockIdx.x * 64;

    // low fragments for all 4 tiles (L2-resident, issue first)
    bf16x8 paT[4][2];
#pragma unroll
    for (int i = 0; i < 4; ++i) {
        const short* lp = lowg + (size_t)(row0 + i * 16 + fr) * 64;
        paT[i][0] = *reinterpret_cast<const bf16x8*>(lp + kg);
        paT[i][1] = *reinterpret_cast<const bf16x8*>(lp + 32 + kg);
    }

    // wreg[n2*2+h] = bf16(wt2[w*128 + n2*16 + fr][h*32 + kg .. +8])
    bf16x8 wreg[16];
#pragma unroll
    for (int n2 = 0; n2 < 8; ++n2)
#pragma unroll
        for (int h = 0; h < 2; ++h) {
            const int kr0 = h * 32 + kg;
            const float* sp = uw + (size_t)(kr0 >> 4) * 16384
                                 + (size_t)(w * 128 + n2 * 16 + fr) * 16 + (kr0 & 15);
            wreg[n2 * 2 + h] = cvt8(ld4(sp), ld4(sp + 4));
        }

#pragma unroll
    for (int i = 0; i < 4; ++i) {
        const int buf = i & 1;
        // MFMA o-eighth into LDS: lane holds out[row=fr][o=w*128+n2*16+kgi*4+j]
#pragma unroll
        for (int n2 = 0; n2 < 8; ++n2) {
            f32x4 c2 = (f32x4){0.f, 0.f, 0.f, 0.f};
            c2 = __builtin_amdgcn_mfma_f32_16x16x32_bf16(wreg[n2 * 2],     paT[i][0], c2, 0, 0, 0);
            c2 = __builtin_amdgcn_mfma_f32_16x16x32_bf16(wreg[n2 * 2 + 1], paT[i][1], c2, 0, 0, 0);
            *reinterpret_cast<f32x4*>(&lbuf[buf][fr][w * 128 + n2 * 16 + kgi * 4]) = c2;
        }

        // ds_writes (and prior tile's ds_reads) complete, then barrier.
        // NO vmcnt drain: the store stream keeps flowing across barriers.
        asm volatile("s_waitcnt lgkmcnt(0)" ::: "memory");
        __builtin_amdgcn_s_barrier();

        // contiguous burst: wave w stores rows w*2, w*2+1 (8 KB linear), NT
        float* ob = out + (size_t)(row0 + i * 16 + w * 2) * O;
        const float* lr = &lbuf[buf][w * 2][0];
#pragma unroll
        for (int r2 = 0; r2 < 2; ++r2)
#pragma unroll
            for (int c = 0; c < 4; ++c) {
                const f32x4 v = *reinterpret_cast<const f32x4*>(
                    lr + r2 * 1026 + c * 256 + lane * 4);
                __builtin_nontemporal_store(
                    v, reinterpret_cast<f32x4*>(ob + (size_t)r2 * O + c * 256 + lane * 4));
            }
    }
}

} // namespace

extern "C" void kernel_launch(void* const* d_in, const int* in_sizes, int n_in,
                              void* d_out, int out_size, void* d_ws, size_t ws_size,
                              hipStream_t stream) {
    const float* hs    = (const float*)d_in[0];  // [4,4096,1024]
    const float* alpha = (const float*)d_in[1];  // [4,4]
    const float* dw    = (const float*)d_in[2];  // [4,16,1024]
    const float* uw    = (const float*)d_in[3];  // [4,1024,16]
    short* lowg = (short*)d_ws;                  // [16384][64] bf16 = 2 MB
    float* outp = (float*)d_out;

    hipLaunchKernelGGL(lora_low_k, dim3(256), dim3(512), 0, stream, hs, alpha, dw, lowg);
    hipLaunchKernelGGL(lora_up_k,  dim3(256), dim3(512), 0, stream, lowg, uw, outp);
}